// Round 5
// baseline (1569.601 us; speedup 1.0000x reference)
//
#include <hip/hip_runtime.h>
#include <math.h>

#define NS 512      // N_way*K_shot support samples
#define NQ 65536    // N_way*Q_query rows
#define DD 1024     // feature dim
#define NW 16       // N_way

typedef __attribute__((ext_vector_type(8))) short short8x;
typedef __attribute__((ext_vector_type(4))) float floatx4;

static __device__ __forceinline__ unsigned short bf_trunc(float x) {
  return (unsigned short)(__float_as_uint(x) >> 16);
}
static __device__ __forceinline__ float bf_tof(unsigned short h) {
  return __uint_as_float(((unsigned)h) << 16);
}
static __device__ __forceinline__ unsigned short bf_rne(float x) {
  unsigned u = __float_as_uint(x);
  return (unsigned short)((u + 0x7FFFu + ((u >> 16) & 1u)) >> 16);
}

// split f32 -> (hi, lo) bf16 pair, swizzled 8B LDS store. k0 multiple of 4.
#define STASH(Hp, Lp, row, k0, v) do {                                      \
    unsigned e_ = (unsigned)((((row) * 32 + (k0)) ^ (((row) & 7) << 3)));   \
    ushort4 h_, l_;                                                         \
    h_.x = bf_trunc((v).x); l_.x = bf_trunc((v).x - bf_tof(h_.x));          \
    h_.y = bf_trunc((v).y); l_.y = bf_trunc((v).y - bf_tof(h_.y));          \
    h_.z = bf_trunc((v).z); l_.z = bf_trunc((v).z - bf_tof(h_.z));          \
    h_.w = bf_trunc((v).w); l_.w = bf_trunc((v).w - bf_tof(h_.w));          \
    *(ushort4*)&Hp[e_] = h_; *(ushort4*)&Lp[e_] = l_;                       \
  } while (0)

// ---------------- row squared-norms (wave per row) — Zs only ----------------
__global__ void row_norms_kernel(const float* __restrict__ X, float* __restrict__ out, int nrows) {
  int gw = (int)((blockIdx.x * blockDim.x + threadIdx.x) >> 6);
  int lane = threadIdx.x & 63;
  if (gw >= nrows) return;
  const float* row = X + (size_t)gw * DD;
  float s = 0.f;
  #pragma unroll
  for (int i = 0; i < 4; ++i) {
    float4 v = *(const float4*)(row + 4 * lane + 256 * i);
    s += v.x * v.x + v.y * v.y + v.z * v.z + v.w * v.w;
  }
  #pragma unroll
  for (int off = 32; off; off >>= 1) s += __shfl_xor(s, off);
  if (lane == 0) out[gw] = s;
}

// ---------------- Kss = rbf(Zs,Zs) + noise*I  (64x64 tiles, fp32 exact) ----------------
__global__ __launch_bounds__(256) void kss_kernel(const float* __restrict__ Zs,
                                                  const float* __restrict__ sn,
                                                  const float* __restrict__ log_ls,
                                                  const float* __restrict__ log_noise,
                                                  float* __restrict__ K) {
  __shared__ __align__(16) float At[16][68];
  __shared__ __align__(16) float Bt[16][68];
  int tid = threadIdx.x;
  int rb = blockIdx.y * 64, cb = blockIdx.x * 64;
  int tx = tid & 15, ty = tid >> 4;
  int srow = tid & 63, skq = (tid >> 6) << 2;
  float acc[4][4] = {};
  for (int kk = 0; kk < DD; kk += 16) {
    __syncthreads();
    float4 a = *(const float4*)(Zs + (size_t)(rb + srow) * DD + kk + skq);
    float4 b = *(const float4*)(Zs + (size_t)(cb + srow) * DD + kk + skq);
    At[skq + 0][srow] = a.x; At[skq + 1][srow] = a.y; At[skq + 2][srow] = a.z; At[skq + 3][srow] = a.w;
    Bt[skq + 0][srow] = b.x; Bt[skq + 1][srow] = b.y; Bt[skq + 2][srow] = b.z; Bt[skq + 3][srow] = b.w;
    __syncthreads();
    #pragma unroll
    for (int k = 0; k < 16; ++k) {
      float4 av = *(const float4*)&At[k][ty * 4];
      float4 bv = *(const float4*)&Bt[k][tx * 4];
      float aa[4] = {av.x, av.y, av.z, av.w};
      float bb[4] = {bv.x, bv.y, bv.z, bv.w};
      #pragma unroll
      for (int i = 0; i < 4; ++i)
        #pragma unroll
        for (int j = 0; j < 4; ++j)
          acc[i][j] = fmaf(aa[i], bb[j], acc[i][j]);
    }
  }
  float inv2 = 0.5f * expf(-2.f * log_ls[0]);
  float noise = expf(2.f * log_noise[0]);
  #pragma unroll
  for (int i = 0; i < 4; ++i)
    #pragma unroll
    for (int j = 0; j < 4; ++j) {
      int r = rb + ty * 4 + i, c = cb + tx * 4 + j;
      float d2 = fmaxf(sn[r] + sn[c] - 2.f * acc[i][j], 0.f);
      float v = expf(-d2 * inv2);
      if (r == c) v += noise;
      K[(size_t)r * NS + c] = v;
    }
}

// ---------------- one-kernel Cholesky + solve ----------------
// Replaces 8x chol_panel + 7x syrk + transpose_fill + cho_solve (17 launches -> 1).
// Phases per panel jb: (a) wave-0 register potrf (shfl broadcasts, no barriers),
// (b) trsm rows below (writes L and its transpose mirror into K's upper tri),
// (c) LDS-tiled fp32 syrk of the trailing submatrix. Then the two triangular
// solves with W in registers (validated cho_solve_v2 logic).
__global__ __launch_bounds__(1024) void chol_all(float* __restrict__ K,
                                                 const int* __restrict__ Ys,
                                                 unsigned short* __restrict__ alpha_t) {
  __shared__ float A[64][68];     // factored diag panel (Ld) for trsm
  __shared__ float SA[64][65];    // syrk A-tile (stride 65: 2-way-free banks)
  __shared__ float SBt[64][68];   // syrk B-tile, transposed [k][c] (b128-aligned)
  __shared__ float idia[64];
  __shared__ float P[64][68];
  __shared__ float WsT[16][68];
  __shared__ float Wblk[64][16];
  __shared__ float invd[64];
  const int tid = threadIdx.x;

  // ================= factorization =================
  for (int jb = 0; jb < 8; ++jb) {
    const int j = jb << 6;
    __syncthreads();
    // ---- (a) wave-0 potrf, rows in registers, shfl column broadcasts ----
    if (tid < 64) {
      const int r = tid;
      float ar[64];
      #pragma unroll
      for (int c4 = 0; c4 < 16; ++c4)
        *(floatx4*)&ar[c4 * 4] = *(const floatx4*)(K + (size_t)(j + r) * NS + j + c4 * 4);
      float myinv = 0.f;
      #pragma unroll
      for (int c = 0; c < 64; ++c) {
        float colv = ar[c];
        float d = __shfl(colv, c);
        float sq = sqrtf(d);
        float inv = 1.f / sq;
        float x = (r > c) ? colv * inv : ((r == c) ? sq : 0.f);
        ar[c] = x;
        if (r == c) myinv = inv;
        #pragma unroll
        for (int k = c + 1; k < 64; ++k) {
          float xk = __shfl(x, k);          // lane k's column-c value
          ar[k] = fmaf(-x, xk, ar[k]);      // junk for r<k region, never read
        }
      }
      idia[r] = myinv;
      #pragma unroll
      for (int c = 0; c < 64; ++c) {
        if (c <= r) {
          A[r][c] = ar[c];
          K[(size_t)(j + r) * NS + j + c] = ar[c];
        }
        if (c < r) K[(size_t)(j + c) * NS + j + r] = ar[c];  // mirror (L^T)
      }
    }
    __syncthreads();
    // ---- (b) trsm: rows below panel, one row per thread ----
    {
      const int r0 = j + 64 + tid;
      if (r0 < NS) {
        float x[64];
        #pragma unroll
        for (int c = 0; c < 64; ++c) {
          float v = K[(size_t)r0 * NS + j + c];
          #pragma unroll
          for (int k = 0; k < c; ++k) v = fmaf(-x[k], A[c][k], v);
          x[c] = v * idia[c];
        }
        #pragma unroll
        for (int c = 0; c < 64; ++c) {
          K[(size_t)r0 * NS + j + c] = x[c];
          K[(size_t)(j + c) * NS + r0] = x[c];  // mirror (L^T)
        }
      }
    }
    // ---- (c) syrk trailing: A22 -= L21 L21^T, 64x64 LDS tiles ----
    const int T = 7 - jb;
    for (int ti = 0; ti < T; ++ti)
      for (int tj = 0; tj <= ti; ++tj) {
        const int rbt = j + 64 + ti * 64, cbt = j + 64 + tj * 64;
        __syncthreads();   // prior compute done reading SA/SBt; trsm K-writes drained
        {
          const int rr = tid >> 4, k4 = (tid & 15) * 4;
          floatx4 av = *(const floatx4*)(K + (size_t)(rbt + rr) * NS + j + k4);
          floatx4 bv = *(const floatx4*)(K + (size_t)(cbt + rr) * NS + j + k4);
          SA[rr][k4 + 0] = av.x; SA[rr][k4 + 1] = av.y;
          SA[rr][k4 + 2] = av.z; SA[rr][k4 + 3] = av.w;
          SBt[k4 + 0][rr] = bv.x; SBt[k4 + 1][rr] = bv.y;
          SBt[k4 + 2][rr] = bv.z; SBt[k4 + 3][rr] = bv.w;
        }
        __syncthreads();
        {
          const int ty = tid & 63, cg = tid >> 6;   // row, col-group (4 cols)
          floatx4 acc = {0.f, 0.f, 0.f, 0.f};
          #pragma unroll 8
          for (int k = 0; k < 64; ++k) {
            float a = SA[ty][k];
            floatx4 b = *(const floatx4*)&SBt[k][cg * 4];
            acc.x = fmaf(a, b.x, acc.x); acc.y = fmaf(a, b.y, acc.y);
            acc.z = fmaf(a, b.z, acc.z); acc.w = fmaf(a, b.w, acc.w);
          }
          float* cp = K + (size_t)(rbt + ty) * NS + cbt + cg * 4;
          floatx4 cv = *(const floatx4*)cp;
          cv.x -= acc.x; cv.y -= acc.y; cv.z -= acc.z; cv.w -= acc.w;
          *(floatx4*)cp = cv;
        }
      }
  }

  // ================= cho_solve: L W = Y, then L^T alpha = W =================
  const int rs = tid >> 4, nn = tid & 15;
  const int pc = nn * 4;
  float w[8];
  #pragma unroll
  for (int k = 0; k < 8; ++k) w[k] = (Ys[rs + 64 * k] == nn) ? 1.f : 0.f;

  // ---- forward ----
  for (int jb = 0; jb < 8; ++jb) {
    const int j = jb << 6;
    __syncthreads();
    #pragma unroll
    for (int k = 0; k < 8; ++k) if (k == jb) Wblk[rs][nn] = w[k];
    *(floatx4*)&P[rs][pc] = *(const floatx4*)(K + (size_t)(j + rs) * NS + j + pc);
    __syncthreads();
    if (tid < 64) {                    // wave-0 lockstep diag solve
      const int n = tid & 15, rq = tid >> 4;
      invd[tid] = 1.f / P[tid][tid];
      float w16[16];
      #pragma unroll
      for (int i = 0; i < 16; ++i) w16[i] = Wblk[rq + 4 * i][n];
      #pragma unroll
      for (int g = 0; g < 16; ++g) {
        floatx4 p[16];
        #pragma unroll
        for (int i = 0; i < 16; ++i) p[i] = *(const floatx4*)&P[rq + 4 * i][4 * g];
        #pragma unroll
        for (int cj = 0; cj < 4; ++cj) {
          const int c = 4 * g + cj;
          float xc = __shfl(w16[c >> 2], ((c & 3) << 4) + n) * invd[c];
          if (rq == (c & 3)) w16[c >> 2] = xc;
          #pragma unroll
          for (int i = 0; i < 16; ++i) {
            int r = rq + 4 * i;
            if (r > c) w16[i] -= p[i][cj] * xc;
          }
        }
      }
      #pragma unroll
      for (int i = 0; i < 16; ++i) WsT[n][rq + 4 * i] = w16[i];
    }
    __syncthreads();
    #pragma unroll
    for (int k = 0; k < 8; ++k) if (k == jb) w[k] = WsT[nn][rs];
    floatx4 wsr[16];
    #pragma unroll
    for (int g = 0; g < 16; ++g) wsr[g] = *(const floatx4*)&WsT[nn][4 * g];
    #pragma unroll
    for (int k = 0; k < 8; ++k) {
      if (k > jb) {
        const float* lrow = K + (size_t)(rs + 64 * k) * NS + j;
        float s = w[k];
        #pragma unroll
        for (int g = 0; g < 16; ++g) {
          floatx4 lv = *(const floatx4*)(lrow + 4 * g);
          s -= lv.x * wsr[g].x + lv.y * wsr[g].y + lv.z * wsr[g].z + lv.w * wsr[g].w;
        }
        w[k] = s;
      }
    }
  }

  // ---- backward ----
  for (int jb = 7; jb >= 0; --jb) {
    const int j = jb << 6;
    __syncthreads();
    #pragma unroll
    for (int k = 0; k < 8; ++k) if (k == jb) Wblk[rs][nn] = w[k];
    *(floatx4*)&P[rs][pc] = *(const floatx4*)(K + (size_t)(j + rs) * NS + j + pc);
    __syncthreads();
    if (tid < 64) {                    // upper-tri solve, columns descending
      const int n = tid & 15, rq = tid >> 4;
      invd[tid] = 1.f / P[tid][tid];
      float w16[16];
      #pragma unroll
      for (int i = 0; i < 16; ++i) w16[i] = Wblk[rq + 4 * i][n];
      #pragma unroll
      for (int g = 15; g >= 0; --g) {
        floatx4 p[16];
        #pragma unroll
        for (int i = 0; i < 16; ++i) p[i] = *(const floatx4*)&P[rq + 4 * i][4 * g];
        #pragma unroll
        for (int cj = 3; cj >= 0; --cj) {
          const int c = 4 * g + cj;
          float xc = __shfl(w16[c >> 2], ((c & 3) << 4) + n) * invd[c];
          if (rq == (c & 3)) w16[c >> 2] = xc;
          #pragma unroll
          for (int i = 0; i < 16; ++i) {
            int r = rq + 4 * i;
            if (r < c) w16[i] -= p[i][cj] * xc;
          }
        }
      }
      #pragma unroll
      for (int i = 0; i < 16; ++i) WsT[n][rq + 4 * i] = w16[i];
    }
    __syncthreads();
    #pragma unroll
    for (int k = 0; k < 8; ++k) if (k == jb) w[k] = WsT[nn][rs];
    floatx4 wsr[16];
    #pragma unroll
    for (int g = 0; g < 16; ++g) wsr[g] = *(const floatx4*)&WsT[nn][4 * g];
    #pragma unroll
    for (int k = 0; k < 8; ++k) {
      if (k < jb) {                    // rows above: read L^T from upper triangle
        const float* lrow = K + (size_t)(rs + 64 * k) * NS + j;
        float s = w[k];
        #pragma unroll
        for (int g = 0; g < 16; ++g) {
          floatx4 lv = *(const floatx4*)(lrow + 4 * g);
          s -= lv.x * wsr[g].x + lv.y * wsr[g].y + lv.z * wsr[g].z + lv.w * wsr[g].w;
        }
        w[k] = s;
      }
    }
  }

  #pragma unroll
  for (int k = 0; k < 8; ++k)
    alpha_t[(size_t)nn * NS + rs + 64 * k] = bf_rne(w[k]);
}

// ---------------- fused: split-bf16 MFMA Gram -> exp -> MFMA PV -> softmax ----------------
__global__ __launch_bounds__(512) void fused_v2(const float* __restrict__ Zq,
                                                const float* __restrict__ Zs,
                                                const float* __restrict__ sn,
                                                const unsigned short* __restrict__ alpha_t,
                                                const float* __restrict__ log_ls,
                                                float* __restrict__ out) {
  __shared__ __align__(16) unsigned short LB[32768];  // 64 KB, unioned
  __shared__ float qnl[128];
  __shared__ float snl[256];
  unsigned short* AhB = LB;            // Zq hi  [128][32]
  unsigned short* AlB = LB + 4096;     // Zq lo
  unsigned short* BhB = LB + 8192;     // Zs hi  [256][32]
  unsigned short* BlB = LB + 16384;    // Zs lo
  unsigned short* KqB = LB;            // Kq bf16 [128][256] (epilogue overlay)

  const int tid = threadIdx.x;
  const int lane = tid & 63;
  const int w = tid >> 6;              // 8 waves: 2(m) x 4(n)
  const int wm = w >> 2, wn = w & 3;
  const int l15 = lane & 15, l4 = lane >> 4;
  const int rb = blockIdx.x * 128;
  const float inv2 = 0.5f * __expf(-2.f * log_ls[0]);
  const unsigned swz = (unsigned)((l15 & 7) << 3);

  if (tid < 128) qnl[tid] = 0.f;
  __syncthreads();

  const int qrow0 = tid >> 3;          // 0..63
  const int qk0 = (tid & 7) * 4;
  const int qrow1 = 64 + qrow0;

  floatx4 facc = {0.f, 0.f, 0.f, 0.f};

  for (int cc = 0; cc < NS; cc += 256) {
    if (tid < 256) snl[tid] = sn[cc + tid];
    floatx4 acc[4][4];
    #pragma unroll
    for (int a = 0; a < 4; ++a)
      #pragma unroll
      for (int b = 0; b < 4; ++b) acc[a][b] = (floatx4){0.f, 0.f, 0.f, 0.f};

    // prefetch kt = 0
    float4 pq0 = *(const float4*)(Zq + (size_t)(rb + qrow0) * DD + qk0);
    float4 pq1 = *(const float4*)(Zq + (size_t)(rb + qrow1) * DD + qk0);
    float4 ps[4];
    #pragma unroll
    for (int u = 0; u < 4; ++u) {
      int idx = tid + (u << 9);
      ps[u] = *(const float4*)(Zs + (size_t)(cc + (idx >> 3)) * DD + ((idx & 7) * 4));
    }

    for (int kt = 0; kt < 32; ++kt) {
      // ---- STORE phase: regs -> swizzled split-bf16 LDS ----
      STASH(AhB, AlB, qrow0, qk0, pq0);
      STASH(AhB, AlB, qrow1, qk0, pq1);
      #pragma unroll
      for (int u = 0; u < 4; ++u) {
        int idx = tid + (u << 9);
        int srow = idx >> 3, sk0 = (idx & 7) * 4;
        STASH(BhB, BlB, srow, sk0, ps[u]);
      }
      if (cc == 0) {  // fold Zq row-norm accumulation into chunk-0 staging
        float s0 = pq0.x * pq0.x + pq0.y * pq0.y + pq0.z * pq0.z + pq0.w * pq0.w;
        float s1 = pq1.x * pq1.x + pq1.y * pq1.y + pq1.z * pq1.z + pq1.w * pq1.w;
        #pragma unroll
        for (int d = 1; d < 8; d <<= 1) { s0 += __shfl_xor(s0, d); s1 += __shfl_xor(s1, d); }
        if ((tid & 7) == 0) { qnl[qrow0] += s0; qnl[qrow1] += s1; }
      }
      __syncthreads();
      // ---- prefetch next iter (hidden under MFMA) ----
      if (kt < 31) {
        int kk2 = (kt + 1) << 5;
        pq0 = *(const float4*)(Zq + (size_t)(rb + qrow0) * DD + kk2 + qk0);
        pq1 = *(const float4*)(Zq + (size_t)(rb + qrow1) * DD + kk2 + qk0);
        #pragma unroll
        for (int u = 0; u < 4; ++u) {
          int idx = tid + (u << 9);
          ps[u] = *(const float4*)(Zs + (size_t)(cc + (idx >> 3)) * DD + kk2 + ((idx & 7) * 4));
        }
      }
      // ---- compute: 16 ds_read_b128 + 48 MFMA ----
      short8x ah[4], al[4], bh[4], bl[4];
      #pragma unroll
      for (int mi = 0; mi < 4; ++mi) {
        unsigned e = (unsigned)((wm * 64 + mi * 16 + l15) * 32 + 8 * l4) ^ swz;
        ah[mi] = *(const short8x*)&AhB[e];
        al[mi] = *(const short8x*)&AlB[e];
      }
      #pragma unroll
      for (int ni = 0; ni < 4; ++ni) {
        unsigned e = (unsigned)((wn * 64 + ni * 16 + l15) * 32 + 8 * l4) ^ swz;
        bh[ni] = *(const short8x*)&BhB[e];
        bl[ni] = *(const short8x*)&BlB[e];
      }
      #pragma unroll
      for (int mi = 0; mi < 4; ++mi)
        #pragma unroll
        for (int ni = 0; ni < 4; ++ni) {
          acc[mi][ni] = __builtin_amdgcn_mfma_f32_16x16x32_bf16(ah[mi], bh[ni], acc[mi][ni], 0, 0, 0);
          acc[mi][ni] = __builtin_amdgcn_mfma_f32_16x16x32_bf16(ah[mi], bl[ni], acc[mi][ni], 0, 0, 0);
          acc[mi][ni] = __builtin_amdgcn_mfma_f32_16x16x32_bf16(al[mi], bh[ni], acc[mi][ni], 0, 0, 0);
        }
      __syncthreads();
    }

    // ---- epilogue: PV B-frags (alpha^T, global/L2), kq -> KqB, PV MFMA ----
    short8x bfr[8];
    #pragma unroll
    for (int s = 0; s < 8; ++s)
      bfr[s] = *(const short8x*)(alpha_t + ((size_t)l15 * NS + cc + 32 * s + 8 * l4));

    #pragma unroll
    for (int mi = 0; mi < 4; ++mi)
      #pragma unroll
      for (int rr = 0; rr < 4; ++rr) {
        int row_l = wm * 64 + mi * 16 + l4 * 4 + rr;
        float qv = qnl[row_l];
        unsigned sw = (unsigned)((row_l & 7) << 3);
        #pragma unroll
        for (int ni = 0; ni < 4; ++ni) {
          int col = wn * 64 + ni * 16 + l15;
          float d2 = fmaxf(qv + snl[col] - 2.f * acc[mi][ni][rr], 0.f);
          float kq = __expf(-d2 * inv2);
          KqB[(unsigned)(row_l * 256 + col) ^ sw] = bf_rne(kq);
        }
      }
    __syncthreads();
    #pragma unroll
    for (int s = 0; s < 8; ++s) {
      unsigned e = (unsigned)((w * 16 + l15) * 256 + 32 * s + 8 * l4) ^ swz;
      short8x ak = *(const short8x*)&KqB[e];
      facc = __builtin_amdgcn_mfma_f32_16x16x32_bf16(ak, bfr[s], facc, 0, 0, 0);
    }
    __syncthreads();
  }

  // ---- softmax over 16 classes (spread across 16-lane groups) ----
  #pragma unroll
  for (int r = 0; r < 4; ++r) {
    float v = facc[r];
    float m = v;
    #pragma unroll
    for (int d = 1; d < 16; d <<= 1) m = fmaxf(m, __shfl_xor(m, d));
    float e = __expf(v - m);
    float s = e;
    #pragma unroll
    for (int d = 1; d < 16; d <<= 1) s += __shfl_xor(s, d);
    out[(size_t)(rb + w * 16 + l4 * 4 + r) * NW + l15] = e / s;
  }
}

extern "C" void kernel_launch(void* const* d_in, const int* in_sizes, int n_in,
                              void* d_out, int out_size, void* d_ws, size_t ws_size,
                              hipStream_t stream) {
  (void)in_sizes; (void)n_in; (void)out_size; (void)ws_size;
  const float* Zs = (const float*)d_in[0];
  const int*   Ys = (const int*)d_in[1];
  const float* Zq = (const float*)d_in[2];
  const float* log_ls = (const float*)d_in[3];
  const float* log_noise = (const float*)d_in[4];
  float* out = (float*)d_out;

  float* ws = (float*)d_ws;
  float* K  = ws;                                   // 512*512 f32
  float* sn = ws + (size_t)NS * NS;                 // 512 f32
  unsigned short* alpha_t = (unsigned short*)(sn + NS);  // [16][512] bf16

  row_norms_kernel<<<128, 256, 0, stream>>>(Zs, sn, NS);
  kss_kernel<<<dim3(8, 8), 256, 0, stream>>>(Zs, sn, log_ls, log_noise, K);
  chol_all<<<1, 1024, 0, stream>>>(K, Ys, alpha_t);
  fused_v2<<<NQ / 128, 512, 0, stream>>>(Zq, Zs, sn, alpha_t, log_ls, out);
}

// Round 6
// 1477.857 us; speedup vs baseline: 1.0621x; 1.0621x over previous
//
#include <hip/hip_runtime.h>
#include <math.h>

#define NS 512      // N_way*K_shot support samples
#define NQ 65536    // N_way*Q_query rows
#define DD 1024     // feature dim
#define NW 16       // N_way

typedef __attribute__((ext_vector_type(8))) short short8x;
typedef __attribute__((ext_vector_type(4))) float floatx4;

static __device__ __forceinline__ unsigned short bf_trunc(float x) {
  return (unsigned short)(__float_as_uint(x) >> 16);
}
static __device__ __forceinline__ float bf_tof(unsigned short h) {
  return __uint_as_float(((unsigned)h) << 16);
}
static __device__ __forceinline__ unsigned short bf_rne(float x) {
  unsigned u = __float_as_uint(x);
  return (unsigned short)((u + 0x7FFFu + ((u >> 16) & 1u)) >> 16);
}

// split f32 -> (hi, lo) bf16 pair, swizzled 8B LDS store. k0 multiple of 4.
#define STASH(Hp, Lp, row, k0, v) do {                                      \
    unsigned e_ = (unsigned)((((row) * 32 + (k0)) ^ (((row) & 7) << 3)));   \
    ushort4 h_, l_;                                                         \
    h_.x = bf_trunc((v).x); l_.x = bf_trunc((v).x - bf_tof(h_.x));          \
    h_.y = bf_trunc((v).y); l_.y = bf_trunc((v).y - bf_tof(h_.y));          \
    h_.z = bf_trunc((v).z); l_.z = bf_trunc((v).z - bf_tof(h_.z));          \
    h_.w = bf_trunc((v).w); l_.w = bf_trunc((v).w - bf_tof(h_.w));          \
    *(ushort4*)&Hp[e_] = h_; *(ushort4*)&Lp[e_] = l_;                       \
  } while (0)

// ---------------- row squared-norms (wave per row) — Zs only ----------------
__global__ void row_norms_kernel(const float* __restrict__ X, float* __restrict__ out, int nrows) {
  int gw = (int)((blockIdx.x * blockDim.x + threadIdx.x) >> 6);
  int lane = threadIdx.x & 63;
  if (gw >= nrows) return;
  const float* row = X + (size_t)gw * DD;
  float s = 0.f;
  #pragma unroll
  for (int i = 0; i < 4; ++i) {
    float4 v = *(const float4*)(row + 4 * lane + 256 * i);
    s += v.x * v.x + v.y * v.y + v.z * v.z + v.w * v.w;
  }
  #pragma unroll
  for (int off = 32; off; off >>= 1) s += __shfl_xor(s, off);
  if (lane == 0) out[gw] = s;
}

// ---------------- Kss = rbf(Zs,Zs) + noise*I  (64x64 tiles, fp32 exact) ----------------
__global__ __launch_bounds__(256) void kss_kernel(const float* __restrict__ Zs,
                                                  const float* __restrict__ sn,
                                                  const float* __restrict__ log_ls,
                                                  const float* __restrict__ log_noise,
                                                  float* __restrict__ K) {
  __shared__ __align__(16) float At[16][68];
  __shared__ __align__(16) float Bt[16][68];
  int tid = threadIdx.x;
  int rb = blockIdx.y * 64, cb = blockIdx.x * 64;
  int tx = tid & 15, ty = tid >> 4;
  int srow = tid & 63, skq = (tid >> 6) << 2;
  float acc[4][4] = {};
  for (int kk = 0; kk < DD; kk += 16) {
    __syncthreads();
    float4 a = *(const float4*)(Zs + (size_t)(rb + srow) * DD + kk + skq);
    float4 b = *(const float4*)(Zs + (size_t)(cb + srow) * DD + kk + skq);
    At[skq + 0][srow] = a.x; At[skq + 1][srow] = a.y; At[skq + 2][srow] = a.z; At[skq + 3][srow] = a.w;
    Bt[skq + 0][srow] = b.x; Bt[skq + 1][srow] = b.y; Bt[skq + 2][srow] = b.z; Bt[skq + 3][srow] = b.w;
    __syncthreads();
    #pragma unroll
    for (int k = 0; k < 16; ++k) {
      float4 av = *(const float4*)&At[k][ty * 4];
      float4 bv = *(const float4*)&Bt[k][tx * 4];
      float aa[4] = {av.x, av.y, av.z, av.w};
      float bb[4] = {bv.x, bv.y, bv.z, bv.w};
      #pragma unroll
      for (int i = 0; i < 4; ++i)
        #pragma unroll
        for (int j = 0; j < 4; ++j)
          acc[i][j] = fmaf(aa[i], bb[j], acc[i][j]);
    }
  }
  float inv2 = 0.5f * expf(-2.f * log_ls[0]);
  float noise = expf(2.f * log_noise[0]);
  #pragma unroll
  for (int i = 0; i < 4; ++i)
    #pragma unroll
    for (int j = 0; j < 4; ++j) {
      int r = rb + ty * 4 + i, c = cb + tx * 4 + j;
      float d2 = fmaxf(sn[r] + sn[c] - 2.f * acc[i][j], 0.f);
      float v = expf(-d2 * inv2);
      if (r == c) v += noise;
      K[(size_t)r * NS + c] = v;
    }
}

// ---------------- panel: wave-0 register potrf + fast trsm + mirror writes ----------------
// potrf: lane r holds row r in ar[64]; column broadcast via __shfl; no barriers.
// trsm: row r0 prefetched into 64 regs; inner substitution reads Ld as broadcast
// float4 (conflict-free); writes L row AND its transpose mirror (upper triangle).
__global__ __launch_bounds__(256) void panel_v2(float* __restrict__ K, int j) {
  __shared__ float Ld[64][68];
  __shared__ float idia_s[64];
  const int tid = threadIdx.x;

  if (tid < 64) {
    const int r = tid;
    float ar[64];
    #pragma unroll
    for (int c4 = 0; c4 < 16; ++c4)
      *(floatx4*)&ar[c4 * 4] = *(const floatx4*)(K + (size_t)(j + r) * NS + j + c4 * 4);
    float myinv = 0.f;
    #pragma unroll
    for (int c = 0; c < 64; ++c) {
      float colv = ar[c];
      float d = __shfl(colv, c);
      float sq = sqrtf(d);
      float inv = 1.f / sq;
      float x = (r > c) ? colv * inv : ((r == c) ? sq : 0.f);
      ar[c] = x;
      if (r == c) myinv = inv;
      #pragma unroll
      for (int k = c + 1; k < 64; ++k) {
        float xk = __shfl(x, k);
        ar[k] = fmaf(-x, xk, ar[k]);   // junk on rows r<=c for k>c, never read
      }
    }
    idia_s[r] = myinv;
    #pragma unroll
    for (int c4 = 0; c4 < 16; ++c4)
      *(floatx4*)&Ld[r][c4 * 4] = *(const floatx4*)&ar[c4 * 4];  // zeros above diag
    #pragma unroll
    for (int c = 0; c < 64; ++c) {
      if (c <= r) K[(size_t)(j + r) * NS + j + c] = ar[c];
      if (c < r)  K[(size_t)(j + c) * NS + j + r] = ar[c];       // diag-block mirror
    }
  }
  __syncthreads();

  // trsm: X * L11^T = A21, one row per thread per batch
  for (int r0 = j + 64 + tid; r0 < NS; r0 += 256) {
    float xr[64];
    #pragma unroll
    for (int c4 = 0; c4 < 16; ++c4)
      *(floatx4*)&xr[c4 * 4] = *(const floatx4*)(K + (size_t)r0 * NS + j + c4 * 4);
    #pragma unroll
    for (int g = 0; g < 16; ++g) {
      float v0 = xr[4 * g + 0], v1 = xr[4 * g + 1], v2 = xr[4 * g + 2], v3 = xr[4 * g + 3];
      for (int kb = 0; kb < g; ++kb) {
        floatx4 x4 = *(const floatx4*)&xr[4 * kb];
        floatx4 l0 = *(const floatx4*)&Ld[4 * g + 0][4 * kb];
        floatx4 l1 = *(const floatx4*)&Ld[4 * g + 1][4 * kb];
        floatx4 l2 = *(const floatx4*)&Ld[4 * g + 2][4 * kb];
        floatx4 l3 = *(const floatx4*)&Ld[4 * g + 3][4 * kb];
        v0 -= x4.x * l0.x + x4.y * l0.y + x4.z * l0.z + x4.w * l0.w;
        v1 -= x4.x * l1.x + x4.y * l1.y + x4.z * l1.z + x4.w * l1.w;
        v2 -= x4.x * l2.x + x4.y * l2.y + x4.z * l2.z + x4.w * l2.w;
        v3 -= x4.x * l3.x + x4.y * l3.y + x4.z * l3.z + x4.w * l3.w;
      }
      const int c0 = 4 * g;
      float x0 = v0 * idia_s[c0 + 0];
      v1 -= x0 * Ld[c0 + 1][c0];
      float x1 = v1 * idia_s[c0 + 1];
      v2 -= x0 * Ld[c0 + 2][c0] + x1 * Ld[c0 + 2][c0 + 1];
      float x2 = v2 * idia_s[c0 + 2];
      v3 -= x0 * Ld[c0 + 3][c0] + x1 * Ld[c0 + 3][c0 + 1] + x2 * Ld[c0 + 3][c0 + 2];
      float x3 = v3 * idia_s[c0 + 3];
      xr[c0 + 0] = x0; xr[c0 + 1] = x1; xr[c0 + 2] = x2; xr[c0 + 3] = x3;
    }
    #pragma unroll
    for (int c4 = 0; c4 < 16; ++c4)
      *(floatx4*)(K + (size_t)r0 * NS + j + c4 * 4) = *(const floatx4*)&xr[c4 * 4];
    #pragma unroll
    for (int c = 0; c < 64; ++c)
      K[(size_t)(j + c) * NS + r0] = xr[c];    // strip mirror (coalesced across lanes)
  }
}

// trailing update A22 -= L21 * L21^T (64x64 tiles, skip strictly-upper tiles)
__global__ __launch_bounds__(256) void syrk_trailing(float* __restrict__ K, int j) {
  int t0 = j + 64;
  int rbt = t0 + blockIdx.y * 64, cbt = t0 + blockIdx.x * 64;
  if (cbt > rbt) return;
  __shared__ float A[64][69];
  __shared__ float B[64][69];
  int tid = threadIdx.x;
  for (int i = tid; i < 64 * 64; i += 256) {
    int r = i >> 6, k = i & 63;
    A[r][k] = K[(size_t)(rbt + r) * NS + j + k];
    B[r][k] = K[(size_t)(cbt + r) * NS + j + k];
  }
  __syncthreads();
  int tx = tid & 15, ty = tid >> 4;
  float acc[4][4] = {};
  for (int k = 0; k < 64; ++k) {
    float aa[4], bb[4];
    #pragma unroll
    for (int i = 0; i < 4; ++i) aa[i] = A[ty * 4 + i][k];
    #pragma unroll
    for (int i = 0; i < 4; ++i) bb[i] = B[tx * 4 + i][k];
    #pragma unroll
    for (int i = 0; i < 4; ++i)
      #pragma unroll
      for (int jj = 0; jj < 4; ++jj)
        acc[i][jj] = fmaf(aa[i], bb[jj], acc[i][jj]);
  }
  #pragma unroll
  for (int i = 0; i < 4; ++i)
    #pragma unroll
    for (int jj = 0; jj < 4; ++jj)
      K[(size_t)(rbt + ty * 4 + i) * NS + cbt + tx * 4 + jj] -= acc[i][jj];
}

// ---------------- cho_solve v2: W in registers, L2-direct panel reads ----------------
// thread (rs,nn): rs=tid>>4 (0..63), nn=tid&15; owns w[k] = W[rs+64k][nn], k=0..7.
// K lower = L, K strictly-upper = L^T (mirrors written by panel_v2).
__global__ __launch_bounds__(1024) void cho_solve_v2(const float* __restrict__ K,
                                                     const int* __restrict__ Ys,
                                                     unsigned short* __restrict__ alpha_t) {
  __shared__ float P[64][68];
  __shared__ float WsT[16][68];
  __shared__ float Wblk[64][16];
  __shared__ float invd[64];
  const int tid = threadIdx.x;
  const int rs = tid >> 4, nn = tid & 15;
  const int pc = nn * 4;

  float w[8];
  #pragma unroll
  for (int k = 0; k < 8; ++k) w[k] = (Ys[rs + 64 * k] == nn) ? 1.f : 0.f;

  // ---- forward: L W = Y ----
  for (int jb = 0; jb < 8; ++jb) {
    const int j = jb << 6;
    __syncthreads();
    #pragma unroll
    for (int k = 0; k < 8; ++k) if (k == jb) Wblk[rs][nn] = w[k];
    *(floatx4*)&P[rs][pc] = *(const floatx4*)(K + (size_t)(j + rs) * NS + j + pc);
    __syncthreads();
    if (tid < 64) {                    // wave-0 lockstep diag solve
      const int n = tid & 15, rq = tid >> 4;
      invd[tid] = 1.f / P[tid][tid];
      float w16[16];
      #pragma unroll
      for (int i = 0; i < 16; ++i) w16[i] = Wblk[rq + 4 * i][n];
      #pragma unroll
      for (int g = 0; g < 16; ++g) {
        floatx4 p[16];
        #pragma unroll
        for (int i = 0; i < 16; ++i) p[i] = *(const floatx4*)&P[rq + 4 * i][4 * g];
        #pragma unroll
        for (int cj = 0; cj < 4; ++cj) {
          const int c = 4 * g + cj;
          float xc = __shfl(w16[c >> 2], ((c & 3) << 4) + n) * invd[c];
          if (rq == (c & 3)) w16[c >> 2] = xc;
          #pragma unroll
          for (int i = 0; i < 16; ++i) {
            int r = rq + 4 * i;
            if (r > c) w16[i] -= p[i][cj] * xc;
          }
        }
      }
      #pragma unroll
      for (int i = 0; i < 16; ++i) WsT[n][rq + 4 * i] = w16[i];
    }
    __syncthreads();
    #pragma unroll
    for (int k = 0; k < 8; ++k) if (k == jb) w[k] = WsT[nn][rs];
    floatx4 wsr[16];
    #pragma unroll
    for (int g = 0; g < 16; ++g) wsr[g] = *(const floatx4*)&WsT[nn][4 * g];
    #pragma unroll
    for (int k = 0; k < 8; ++k) {
      if (k > jb) {
        const float* lrow = K + (size_t)(rs + 64 * k) * NS + j;
        float s = w[k];
        #pragma unroll
        for (int g = 0; g < 16; ++g) {
          floatx4 lv = *(const floatx4*)(lrow + 4 * g);
          s -= lv.x * wsr[g].x + lv.y * wsr[g].y + lv.z * wsr[g].z + lv.w * wsr[g].w;
        }
        w[k] = s;
      }
    }
  }

  // ---- backward: L^T alpha = W ----
  for (int jb = 7; jb >= 0; --jb) {
    const int j = jb << 6;
    __syncthreads();
    #pragma unroll
    for (int k = 0; k < 8; ++k) if (k == jb) Wblk[rs][nn] = w[k];
    *(floatx4*)&P[rs][pc] = *(const floatx4*)(K + (size_t)(j + rs) * NS + j + pc);
    __syncthreads();
    if (tid < 64) {                    // upper-tri solve, columns descending
      const int n = tid & 15, rq = tid >> 4;
      invd[tid] = 1.f / P[tid][tid];
      float w16[16];
      #pragma unroll
      for (int i = 0; i < 16; ++i) w16[i] = Wblk[rq + 4 * i][n];
      #pragma unroll
      for (int g = 15; g >= 0; --g) {
        floatx4 p[16];
        #pragma unroll
        for (int i = 0; i < 16; ++i) p[i] = *(const floatx4*)&P[rq + 4 * i][4 * g];
        #pragma unroll
        for (int cj = 3; cj >= 0; --cj) {
          const int c = 4 * g + cj;
          float xc = __shfl(w16[c >> 2], ((c & 3) << 4) + n) * invd[c];
          if (rq == (c & 3)) w16[c >> 2] = xc;
          #pragma unroll
          for (int i = 0; i < 16; ++i) {
            int r = rq + 4 * i;
            if (r < c) w16[i] -= p[i][cj] * xc;
          }
        }
      }
      #pragma unroll
      for (int i = 0; i < 16; ++i) WsT[n][rq + 4 * i] = w16[i];
    }
    __syncthreads();
    #pragma unroll
    for (int k = 0; k < 8; ++k) if (k == jb) w[k] = WsT[nn][rs];
    floatx4 wsr[16];
    #pragma unroll
    for (int g = 0; g < 16; ++g) wsr[g] = *(const floatx4*)&WsT[nn][4 * g];
    #pragma unroll
    for (int k = 0; k < 8; ++k) {
      if (k < jb) {                    // rows above: read L^T from upper triangle
        const float* lrow = K + (size_t)(rs + 64 * k) * NS + j;
        float s = w[k];
        #pragma unroll
        for (int g = 0; g < 16; ++g) {
          floatx4 lv = *(const floatx4*)(lrow + 4 * g);
          s -= lv.x * wsr[g].x + lv.y * wsr[g].y + lv.z * wsr[g].z + lv.w * wsr[g].w;
        }
        w[k] = s;
      }
    }
  }

  #pragma unroll
  for (int k = 0; k < 8; ++k)
    alpha_t[(size_t)nn * NS + rs + 64 * k] = bf_rne(w[k]);
}

// ---------------- fused: split-bf16 MFMA Gram -> exp -> MFMA PV -> softmax ----------------
__global__ __launch_bounds__(512) void fused_v2(const float* __restrict__ Zq,
                                                const float* __restrict__ Zs,
                                                const float* __restrict__ sn,
                                                const unsigned short* __restrict__ alpha_t,
                                                const float* __restrict__ log_ls,
                                                float* __restrict__ out) {
  __shared__ __align__(16) unsigned short LB[32768];  // 64 KB, unioned
  __shared__ float qnl[128];
  __shared__ float snl[256];
  unsigned short* AhB = LB;            // Zq hi  [128][32]
  unsigned short* AlB = LB + 4096;     // Zq lo
  unsigned short* BhB = LB + 8192;     // Zs hi  [256][32]
  unsigned short* BlB = LB + 16384;    // Zs lo
  unsigned short* KqB = LB;            // Kq bf16 [128][256] (epilogue overlay)

  const int tid = threadIdx.x;
  const int lane = tid & 63;
  const int w = tid >> 6;              // 8 waves: 2(m) x 4(n)
  const int wm = w >> 2, wn = w & 3;
  const int l15 = lane & 15, l4 = lane >> 4;
  const int rb = blockIdx.x * 128;
  const float inv2 = 0.5f * __expf(-2.f * log_ls[0]);
  const unsigned swz = (unsigned)((l15 & 7) << 3);

  if (tid < 128) qnl[tid] = 0.f;
  __syncthreads();

  const int qrow0 = tid >> 3;          // 0..63
  const int qk0 = (tid & 7) * 4;
  const int qrow1 = 64 + qrow0;

  floatx4 facc = {0.f, 0.f, 0.f, 0.f};

  for (int cc = 0; cc < NS; cc += 256) {
    if (tid < 256) snl[tid] = sn[cc + tid];
    floatx4 acc[4][4];
    #pragma unroll
    for (int a = 0; a < 4; ++a)
      #pragma unroll
      for (int b = 0; b < 4; ++b) acc[a][b] = (floatx4){0.f, 0.f, 0.f, 0.f};

    // prefetch kt = 0
    float4 pq0 = *(const float4*)(Zq + (size_t)(rb + qrow0) * DD + qk0);
    float4 pq1 = *(const float4*)(Zq + (size_t)(rb + qrow1) * DD + qk0);
    float4 ps[4];
    #pragma unroll
    for (int u = 0; u < 4; ++u) {
      int idx = tid + (u << 9);
      ps[u] = *(const float4*)(Zs + (size_t)(cc + (idx >> 3)) * DD + ((idx & 7) * 4));
    }

    for (int kt = 0; kt < 32; ++kt) {
      // ---- STORE phase: regs -> swizzled split-bf16 LDS ----
      STASH(AhB, AlB, qrow0, qk0, pq0);
      STASH(AhB, AlB, qrow1, qk0, pq1);
      #pragma unroll
      for (int u = 0; u < 4; ++u) {
        int idx = tid + (u << 9);
        int srow = idx >> 3, sk0 = (idx & 7) * 4;
        STASH(BhB, BlB, srow, sk0, ps[u]);
      }
      if (cc == 0) {  // fold Zq row-norm accumulation into chunk-0 staging
        float s0 = pq0.x * pq0.x + pq0.y * pq0.y + pq0.z * pq0.z + pq0.w * pq0.w;
        float s1 = pq1.x * pq1.x + pq1.y * pq1.y + pq1.z * pq1.z + pq1.w * pq1.w;
        #pragma unroll
        for (int d = 1; d < 8; d <<= 1) { s0 += __shfl_xor(s0, d); s1 += __shfl_xor(s1, d); }
        if ((tid & 7) == 0) { qnl[qrow0] += s0; qnl[qrow1] += s1; }
      }
      __syncthreads();
      // ---- prefetch next iter (hidden under MFMA) ----
      if (kt < 31) {
        int kk2 = (kt + 1) << 5;
        pq0 = *(const float4*)(Zq + (size_t)(rb + qrow0) * DD + kk2 + qk0);
        pq1 = *(const float4*)(Zq + (size_t)(rb + qrow1) * DD + kk2 + qk0);
        #pragma unroll
        for (int u = 0; u < 4; ++u) {
          int idx = tid + (u << 9);
          ps[u] = *(const float4*)(Zs + (size_t)(cc + (idx >> 3)) * DD + kk2 + ((idx & 7) * 4));
        }
      }
      // ---- compute: 16 ds_read_b128 + 48 MFMA ----
      short8x ah[4], al[4], bh[4], bl[4];
      #pragma unroll
      for (int mi = 0; mi < 4; ++mi) {
        unsigned e = (unsigned)((wm * 64 + mi * 16 + l15) * 32 + 8 * l4) ^ swz;
        ah[mi] = *(const short8x*)&AhB[e];
        al[mi] = *(const short8x*)&AlB[e];
      }
      #pragma unroll
      for (int ni = 0; ni < 4; ++ni) {
        unsigned e = (unsigned)((wn * 64 + ni * 16 + l15) * 32 + 8 * l4) ^ swz;
        bh[ni] = *(const short8x*)&BhB[e];
        bl[ni] = *(const short8x*)&BlB[e];
      }
      #pragma unroll
      for (int mi = 0; mi < 4; ++mi)
        #pragma unroll
        for (int ni = 0; ni < 4; ++ni) {
          acc[mi][ni] = __builtin_amdgcn_mfma_f32_16x16x32_bf16(ah[mi], bh[ni], acc[mi][ni], 0, 0, 0);
          acc[mi][ni] = __builtin_amdgcn_mfma_f32_16x16x32_bf16(ah[mi], bl[ni], acc[mi][ni], 0, 0, 0);
          acc[mi][ni] = __builtin_amdgcn_mfma_f32_16x16x32_bf16(al[mi], bh[ni], acc[mi][ni], 0, 0, 0);
        }
      __syncthreads();
    }

    // ---- epilogue: PV B-frags (alpha^T, global/L2), kq -> KqB, PV MFMA ----
    short8x bfr[8];
    #pragma unroll
    for (int s = 0; s < 8; ++s)
      bfr[s] = *(const short8x*)(alpha_t + ((size_t)l15 * NS + cc + 32 * s + 8 * l4));

    #pragma unroll
    for (int mi = 0; mi < 4; ++mi)
      #pragma unroll
      for (int rr = 0; rr < 4; ++rr) {
        int row_l = wm * 64 + mi * 16 + l4 * 4 + rr;
        float qv = qnl[row_l];
        unsigned sw = (unsigned)((row_l & 7) << 3);
        #pragma unroll
        for (int ni = 0; ni < 4; ++ni) {
          int col = wn * 64 + ni * 16 + l15;
          float d2 = fmaxf(qv + snl[col] - 2.f * acc[mi][ni][rr], 0.f);
          float kq = __expf(-d2 * inv2);
          KqB[(unsigned)(row_l * 256 + col) ^ sw] = bf_rne(kq);
        }
      }
    __syncthreads();
    #pragma unroll
    for (int s = 0; s < 8; ++s) {
      unsigned e = (unsigned)((w * 16 + l15) * 256 + 32 * s + 8 * l4) ^ swz;
      short8x ak = *(const short8x*)&KqB[e];
      facc = __builtin_amdgcn_mfma_f32_16x16x32_bf16(ak, bfr[s], facc, 0, 0, 0);
    }
    __syncthreads();
  }

  // ---- softmax over 16 classes (spread across 16-lane groups) ----
  #pragma unroll
  for (int r = 0; r < 4; ++r) {
    float v = facc[r];
    float m = v;
    #pragma unroll
    for (int d = 1; d < 16; d <<= 1) m = fmaxf(m, __shfl_xor(m, d));
    float e = __expf(v - m);
    float s = e;
    #pragma unroll
    for (int d = 1; d < 16; d <<= 1) s += __shfl_xor(s, d);
    out[(size_t)(rb + w * 16 + l4 * 4 + r) * NW + l15] = e / s;
  }
}

extern "C" void kernel_launch(void* const* d_in, const int* in_sizes, int n_in,
                              void* d_out, int out_size, void* d_ws, size_t ws_size,
                              hipStream_t stream) {
  (void)in_sizes; (void)n_in; (void)out_size; (void)ws_size;
  const float* Zs = (const float*)d_in[0];
  const int*   Ys = (const int*)d_in[1];
  const float* Zq = (const float*)d_in[2];
  const float* log_ls = (const float*)d_in[3];
  const float* log_noise = (const float*)d_in[4];
  float* out = (float*)d_out;

  float* ws = (float*)d_ws;
  float* K  = ws;                                   // 512*512 f32
  float* sn = ws + (size_t)NS * NS;                 // 512 f32
  unsigned short* alpha_t = (unsigned short*)(sn + NS);  // [16][512] bf16

  row_norms_kernel<<<128, 256, 0, stream>>>(Zs, sn, NS);
  kss_kernel<<<dim3(8, 8), 256, 0, stream>>>(Zs, sn, log_ls, log_noise, K);
  for (int j = 0; j < NS; j += 64) {
    panel_v2<<<1, 256, 0, stream>>>(K, j);
    int rows = NS - j - 64;
    if (rows > 0) {
      int t = rows / 64;
      syrk_trailing<<<dim3(t, t), 256, 0, stream>>>(K, j);
    }
  }
  cho_solve_v2<<<1, 1024, 0, stream>>>(K, Ys, alpha_t);
  fused_v2<<<NQ / 128, 512, 0, stream>>>(Zq, Zs, sn, alpha_t, log_ls, out);
}